// Round 5
// baseline (354.634 us; speedup 1.0000x reference)
//
#include <hip/hip_runtime.h>

// MVDR oracle beamformer — MI355X (gfx950)
// R5: granularity rewrite. R4 proved deep MLP (VGPR 132, 64 loads in flight)
//   does NOT lift the ~1.9 TB/s plateau -> bottleneck is request granularity
//   (256 B/wave dword granules from ~12K concurrent 617KB-strided streams
//   thrash DRAM rows; the 6.3 TB/s ceiling is a float4 number).
// Phase A: block = (chunk, n, m), 320 thr, ALL 257 f. LDS dbuf 2-t slab
//   S[2][16][514] (64.25 KB). Staging = float2 cooperative over 16 contiguous
//   2056-B plane-spans per slab; reg-staged, sched_barrier-pinned issue-early,
//   write-late. Compute: tid<257 owns f, same 36-pair FMA order as before.
// Phase B1: float4 chunk reduction (unchanged).
// Phase B2: streaming solve (unchanged).
// Phase C: beamform, 4 j per thread -> all float4 loads/stores.

constexpr int N_  = 8;
constexpr int C_  = 8;
constexpr int T_  = 600;
constexpr int F_  = 257;
constexpr int TF_  = T_ * F_;       // 154200
constexpr int CTF_ = C_ * TF_;      // 1233600
constexpr int NSTR_ = 2 * CTF_;     // per-batch stride in inputs
constexpr int NF_  = N_ * F_;       // 2056
constexpr int NPAIR_ = 36;          // lower-triangle pairs of 8x8 Hermitian
constexpr float LOADC_ = 7.0710678118654755e-4f;  // 0.001/sqrt(2)
constexpr float INV_T_ = 1.0f / 600.0f;

#define SBAR() __builtin_amdgcn_sched_barrier(0)

struct cx { float r, i; };
__device__ __forceinline__ cx cmul(cx a, cx b) { return {a.r*b.r - a.i*b.i, a.r*b.i + a.i*b.r}; }
__device__ __forceinline__ cx csub(cx a, cx b) { return {a.r - b.r, a.i - b.i}; }
__device__ __forceinline__ cx cconj(cx a) { return {a.r, -a.i}; }
__device__ __forceinline__ cx cinv(cx a) {
    float id = 1.0f / (a.r*a.r + a.i*a.i);
    return {a.r*id, -a.i*id};
}
__device__ __forceinline__ cx cmadd(cx acc, cx a, cx b) {
    acc.r += a.r*b.r - a.i*b.i;
    acc.i += a.r*b.i + a.i*b.r;
    return acc;
}

// ---------------------------------------------------------------------------
// Phase A. grid (TSPLIT, N, 2), block 320 (5 waves).
// Slab = 2 consecutive t, 16 planes (re c=0..7, im c=0..7), full 257-f rows:
// per plane 514 contiguous floats (t0 even -> float2-aligned). 4112 float2
// cooperative loads -> 13 per thread. LDS S[2][16][514], dbuf, 1 sync/slab.
// Partial layout (unchanged): part[((m*TSPLIT+chunk)*72 + 2p+ri)*NF + n*F + f]
// ---------------------------------------------------------------------------
template<int TSPLIT>
__global__ __launch_bounds__(320, 3) void cov_partial(
        const float* __restrict__ mix, const float* __restrict__ noi,
        float* __restrict__ part) {
    constexpr int TCHUNK = T_ / TSPLIT;
    static_assert(TCHUNK % 2 == 0, "TB=2 slabs need even TCHUNK");
    constexpr int NS = TCHUNK / 2;
    constexpr int NE = 16 * 257;            // float2 elements per slab: 4112
    constexpr int KMAX = (NE + 319) / 320;  // 13

    __shared__ float S[2][16][514];   // 65792 B, 2 blocks/CU

    const int tid = threadIdx.x;
    const int chunk = blockIdx.x;
    const int n = blockIdx.y;
    const int m = blockIdx.z;
    const float* src = (m ? mix : noi) + (size_t)n * NSTR_;
    const int tBase = chunk * TCHUNK;

    // Per-thread cooperative element list (slab-invariant offsets).
    int gOff[KMAX], lOff[KMAX];
#pragma unroll
    for (int kk = 0; kk < KMAX; ++kk) {
        int e = tid + 320 * kk;
        if (e < NE) {
            int pl = e / 257;                 // plane 0..15
            int off2 = (e - pl * 257) * 2;    // float offset within 514-span
            int c = pl & 7;
            gOff[kk] = ((pl < 8) ? c * TF_ : CTF_ + c * TF_) + off2;
            lOff[kk] = pl * 514 + off2;
        } else { gOff[kk] = 0; lOff[kk] = -1; }
    }

    float2 rg[KMAX];
    auto stageRegs = [&](int t0) {            // 13 x 8B contiguous-span loads
        const int tF = t0 * F_;
#pragma unroll
        for (int kk = 0; kk < KMAX; ++kk)
            if (lOff[kk] >= 0)
                rg[kk] = *(const float2*)(src + (size_t)(gOff[kk] + tF));
    };
    auto writeLDS = [&](int buf) {            // vmcnt waits land here (late)
        float* b = &S[buf][0][0];
#pragma unroll
        for (int kk = 0; kk < KMAX; ++kk)
            if (lOff[kk] >= 0)
                *(float2*)(b + lOff[kk]) = rg[kk];
    };

    float accr[NPAIR_], acci[NPAIR_];
#pragma unroll
    for (int p = 0; p < NPAIR_; ++p) { accr[p] = 0.f; acci[p] = 0.f; }

    auto consume = [&](int buf) {
        if (tid < F_) {
#pragma unroll
            for (int tt = 0; tt < 2; ++tt) {  // t ascending, same order as R0
                float re[C_], im[C_];
#pragma unroll
                for (int c = 0; c < C_; ++c) {
                    re[c] = S[buf][c][tt * 257 + tid];
                    im[c] = S[buf][8 + c][tt * 257 + tid];
                }
                int p = 0;
#pragma unroll
                for (int c = 0; c < C_; ++c) {
#pragma unroll
                    for (int d = 0; d <= c; ++d, ++p) {
                        accr[p] += re[c]*re[d] + im[c]*im[d];
                        acci[p] += im[c]*re[d] - re[c]*im[d];
                    }
                }
            }
        }
    };

    // Prologue: slab 0.
    stageRegs(tBase);
    SBAR();
    writeLDS(0);
    __syncthreads();

    for (int k = 0; k < NS; ++k) {
        const bool more = (k + 1 < NS);
        if (more) { stageRegs(tBase + 2 * (k + 1)); SBAR(); }  // issue-early
        consume(k & 1);                                        // hide latency
        if (more) writeLDS((k + 1) & 1);                       // write-late
        __syncthreads();
    }

    if (tid < F_) {
        float* out = part + (size_t)((m * TSPLIT + chunk) * 72) * NF_ + n * F_ + tid;
#pragma unroll
        for (int p = 0; p < NPAIR_; ++p) {
            out[(size_t)(2*p)   * NF_] = accr[p];
            out[(size_t)(2*p+1) * NF_] = acci[p];
        }
    }
}

// ---------------------------------------------------------------------------
// Phase B1: reduce the chunks into the chunk-0 slot, float4-vectorized.
// ---------------------------------------------------------------------------
__global__ __launch_bounds__(256) void reduce_cov(float* __restrict__ part, int tsplit) {
    int flat = blockIdx.x * 256 + threadIdx.x;
    constexpr int NQ4 = NF_ / 4;   // 514
    if (flat >= 2 * 72 * NQ4) return;
    int idx4 = flat % NQ4;
    int z = flat / NQ4;          // z = m*72 + q
    int m = z / 72;
    int q = z % 72;
    const float4* p4 = (const float4*)(part) + ((size_t)((m * tsplit) * 72 + q) * NF_) / 4 + idx4;
    float4 s = {0.f, 0.f, 0.f, 0.f};
    for (int ch = 0; ch < tsplit; ++ch) {
        float4 v = p4[(size_t)(ch * 72) * NF_ / 4];
        s.x += v.x; s.y += v.y; s.z += v.z; s.w += v.w;
    }
    *(float4*)((float*)part + (size_t)((m * tsplit) * 72 + q) * NF_ + idx4 * 4) = s;
}

// ---------------------------------------------------------------------------
// Phase B2: streaming solve. One thread per (n,f). yBase = tsplit*72*NF_.
// ---------------------------------------------------------------------------
__global__ __launch_bounds__(64, 1) void solve_w(
        const float* __restrict__ part, float* __restrict__ W, size_t yBase) {
    int idx = blockIdx.x * 64 + threadIdx.x;  // idx = n*F + f
    if (idx >= NF_) return;

    const float* pv = part + idx;            // m=0, chunk 0
    const float* py = part + yBase + idx;    // m=1, chunk 0

    cx M[64];
#pragma unroll
    for (int c = 0; c < 8; ++c) {
#pragma unroll
        for (int d = 0; d <= c; ++d) {
            int p = c*(c+1)/2 + d;
            cx val = { pv[(size_t)(2*p) * NF_] * INV_T_,
                       pv[(size_t)(2*p+1) * NF_] * INV_T_ };
            if (d == c) { val.r += LOADC_; val.i += LOADC_; }
            M[c*8 + d] = val;
            if (d < c) M[d*8 + c] = cconj(val);
        }
    }

    // In-place Gauss-Jordan inverse, no pivoting (diagonally dominant).
#pragma unroll
    for (int k = 0; k < 8; ++k) {
        cx p = cinv(M[k*8 + k]);
        M[k*8 + k] = p;
#pragma unroll
        for (int j = 0; j < 8; ++j) {
            if (j != k) M[k*8 + j] = cmul(M[k*8 + j], p);
        }
#pragma unroll
        for (int i = 0; i < 8; ++i) {
            if (i == k) continue;
            cx fkt = M[i*8 + k];
#pragma unroll
            for (int j = 0; j < 8; ++j) {
                if (j != k) M[i*8 + j] = csub(M[i*8 + j], cmul(fkt, M[k*8 + j]));
            }
            cx t = cmul(fkt, p);
            M[i*8 + k] = { -t.r, -t.i };
        }
    }

    cx tr = {0.f, 0.f};
    cx g0[8];
#pragma unroll
    for (int c = 0; c < 8; ++c) g0[c] = (cx){0.f, 0.f};

#pragma unroll
    for (int a = 0; a < 8; ++a) {
#pragma unroll
        for (int b = 0; b <= a; ++b) {
            int p = a*(a+1)/2 + b;
            cx yv = { py[(size_t)(2*p) * NF_] * INV_T_,
                      py[(size_t)(2*p+1) * NF_] * INV_T_ };
            tr = cmadd(tr, M[b*8 + a], yv);
            if (a != b) tr = cmadd(tr, M[a*8 + b], cconj(yv));
            if (b == 0) {
#pragma unroll
                for (int i = 0; i < 8; ++i) g0[i] = cmadd(g0[i], M[i*8 + a], yv);
            }
        }
    }

    cx l = { tr.r - 8.0f, tr.i - 8.0f };
    float iden = 1.0f / (l.r*l.r + l.i*l.i);

    float* w = W + (size_t)idx * 16;
#pragma unroll
    for (int c = 0; c < 8; ++c) {
        cx ge = g0[c];
        if (c == 0) ge.r -= 1.0f;
        w[2*c]     = (ge.r*l.r + ge.i*l.i) * iden;
        w[2*c + 1] = (ge.r*l.i - ge.i*l.r) * iden;
    }
}

// ---------------------------------------------------------------------------
// Phase C: beamform, float4-wide. Thread owns j = 4u..4u+3 (contiguous).
// grid (ceil((TF/4)/256), N), block 256. All loads/stores 16 B.
// ---------------------------------------------------------------------------
__global__ __launch_bounds__(256) void beamform(
        const float* __restrict__ mix, const float* __restrict__ W,
        float* __restrict__ out) {
    constexpr int U = TF_ / 4;   // 38550
    int n = blockIdx.y;
    int u = blockIdx.x * 256 + threadIdx.x;
    if (u >= U) return;
    int j0 = 4 * u;
    int f0 = j0 % F_;

    // 4 W rows (16 floats each), L2-resident.
    float4 wv[4][4];
#pragma unroll
    for (int i = 0; i < 4; ++i) {
        int fi = f0 + i; if (fi >= F_) fi -= F_;
        const float4* wr = (const float4*)(W + (size_t)(n * F_ + fi) * 16);
        wv[i][0] = wr[0]; wv[i][1] = wr[1]; wv[i][2] = wr[2]; wv[i][3] = wr[3];
    }

    const float* base = mix + (size_t)n * NSTR_ + j0;
    float xr[4] = {0.f,0.f,0.f,0.f}, xi[4] = {0.f,0.f,0.f,0.f};
#pragma unroll
    for (int c = 0; c < C_; ++c) {
        float4 yr4 = *(const float4*)(base + (size_t)c * TF_);
        float4 yi4 = *(const float4*)(base + (size_t)c * TF_ + CTF_);
        float yrA[4] = {yr4.x, yr4.y, yr4.z, yr4.w};
        float yiA[4] = {yi4.x, yi4.y, yi4.z, yi4.w};
#pragma unroll
        for (int i = 0; i < 4; ++i) {
            float wr_ = (c & 1) ? wv[i][c >> 1].z : wv[i][c >> 1].x;
            float wi_ = (c & 1) ? wv[i][c >> 1].w : wv[i][c >> 1].y;
            xr[i] += wr_*yrA[i] - wi_*yiA[i];
            xi[i] += wr_*yiA[i] + wi_*yrA[i];
        }
    }
    float* op = out + (size_t)n * (2 * TF_);
    *(float4*)(op + j0)       = make_float4(xr[0], xr[1], xr[2], xr[3]);
    *(float4*)(op + TF_ + j0) = make_float4(xi[0], xi[1], xi[2], xi[3]);
}

extern "C" void kernel_launch(void* const* d_in, const int* in_sizes, int n_in,
                              void* d_out, int out_size, void* d_ws, size_t ws_size,
                              hipStream_t stream) {
    const float* mix = (const float*)d_in[0];
    // d_in[1] = target, unused by the reference
    const float* noi = (const float*)d_in[2];

    const size_t need30 = ((size_t)2 * 30 * 72 * NF_ + (size_t)16 * NF_) * 4; // ~35.6 MB
    float* part = (float*)d_ws;
    int tsplit;
    if (ws_size >= need30) {
        tsplit = 30;   // 480 blocks x 5 waves, 2 blocks/CU -> 94% slot fill
        cov_partial<30><<<dim3(30, N_, 2), 320, 0, stream>>>(mix, noi, part);
    } else {
        tsplit = 25;   // 400 blocks fallback (ws >= 29.7 MB known-good)
        cov_partial<25><<<dim3(25, N_, 2), 320, 0, stream>>>(mix, noi, part);
    }
    float* W = part + (size_t)2 * tsplit * 72 * NF_;

    reduce_cov<<<dim3((2 * 72 * (NF_ / 4) + 255) / 256), 256, 0, stream>>>(part, tsplit);
    solve_w<<<dim3((NF_ + 63) / 64), 64, 0, stream>>>(part, W, (size_t)tsplit * 72 * NF_);
    beamform<<<dim3((TF_ / 4 + 255) / 256, N_), 256, 0, stream>>>(mix, W, (float*)d_out);
}

// Round 6
// 252.163 us; speedup vs baseline: 1.4064x; 1.4064x over previous
//
#include <hip/hip_runtime.h>

// MVDR oracle beamformer — MI355X (gfx950)
// R6: (1) cov_partial = R5's contiguous-slab LDS design MINUS the spills
//     (R5 evidence: VGPR=84 << need, WRITE_SIZE doubled = scratch traffic;
//     cause = __launch_bounds__(320,3) clamp + 26-reg persistent offset
//     arrays). Now (320,2), offsets recomputed inline, no guards (wrap).
//     (2) solve_w rewritten wave-parallel: lane (i,j) owns M[i][j]; GJ via
//     shuffles. 2056 waves (~8/CU) instead of 33 waves chip-wide.
//     (3) beamform float4 (R5), reduce_cov float4 (unchanged).

constexpr int N_  = 8;
constexpr int C_  = 8;
constexpr int T_  = 600;
constexpr int F_  = 257;
constexpr int TF_  = T_ * F_;       // 154200
constexpr int CTF_ = C_ * TF_;      // 1233600
constexpr int NSTR_ = 2 * CTF_;     // per-batch stride in inputs
constexpr int NF_  = N_ * F_;       // 2056
constexpr int NPAIR_ = 36;          // lower-triangle pairs of 8x8 Hermitian
constexpr float LOADC_ = 7.0710678118654755e-4f;  // 0.001/sqrt(2)
constexpr float INV_T_ = 1.0f / 600.0f;

#define SBAR() __builtin_amdgcn_sched_barrier(0)

struct cx { float r, i; };
__device__ __forceinline__ cx cmul(cx a, cx b) { return {a.r*b.r - a.i*b.i, a.r*b.i + a.i*b.r}; }
__device__ __forceinline__ cx csub(cx a, cx b) { return {a.r - b.r, a.i - b.i}; }
__device__ __forceinline__ cx cinv(cx a) {
    float id = 1.0f / (a.r*a.r + a.i*a.i);
    return {a.r*id, -a.i*id};
}
__device__ __forceinline__ cx cmadd(cx acc, cx a, cx b) {
    acc.r += a.r*b.r - a.i*b.i;
    acc.i += a.r*b.i + a.i*b.r;
    return acc;
}

// ---------------------------------------------------------------------------
// Phase A. grid (TSPLIT, N, 2), block 320 (5 waves).
// Slab = 2 consecutive t, 16 planes (re c=0..7, im c=0..7): per plane a
// CONTIGUOUS 514-float (2056 B) span, float2-aligned (t0 even). 4112 float2
// units staged cooperatively, 13/thread (units >= 4112 wrap -> benign dup
// writes). LDS S[2][16][514] (65.8 KB) double-buffered, 2 blocks/CU.
// Registers: 72 acc + 26 staging float2 + 16 re/im + temps ~ 135 (fits 204
// at 10 waves/CU; launch_bounds(320,2) caps at 256 -> no spill).
// Partial layout (unchanged): part[((m*TSPLIT+chunk)*72 + 2p+ri)*NF + n*F + f]
// ---------------------------------------------------------------------------
template<int TSPLIT>
__global__ __launch_bounds__(320, 2) void cov_partial(
        const float* __restrict__ mix, const float* __restrict__ noi,
        float* __restrict__ part) {
    constexpr int TCHUNK = T_ / TSPLIT;
    static_assert(TCHUNK % 2 == 0, "TB=2 slabs need even TCHUNK");
    constexpr int NS = TCHUNK / 2;
    constexpr int NE2 = 16 * 257;           // float2 units per slab: 4112
    constexpr int KU = 13;                  // ceil(4112/320)

    __shared__ float S[2][16][514];         // 65792 B

    const int tid = threadIdx.x;
    const int chunk = blockIdx.x;
    const int n = blockIdx.y;
    const int m = blockIdx.z;
    const float* src = (m ? mix : noi) + (size_t)n * NSTR_;
    const int tBase = chunk * TCHUNK;

    float2 rg[KU];
    auto stage = [&](int t0) {              // 13 x 8B loads from 2KB spans
        const size_t tF = (size_t)t0 * 257;
#pragma unroll
        for (int kk = 0; kk < KU; ++kk) {
            int u = tid + 320 * kk; int e = (u >= NE2) ? u - NE2 : u;
            int pl = e / 257; int r = e - pl * 257;
            int c = pl & 7;
            size_t goff = ((pl < 8) ? (size_t)c * TF_
                                    : (size_t)CTF_ + (size_t)c * TF_) + 2 * r;
            rg[kk] = *(const float2*)(src + goff + tF);
        }
    };
    auto writeL = [&](int buf) {            // vmcnt waits land here (late)
        float* b = &S[buf][0][0];
#pragma unroll
        for (int kk = 0; kk < KU; ++kk) {
            int u = tid + 320 * kk; int e = (u >= NE2) ? u - NE2 : u;
            int pl = e / 257; int r = e - pl * 257;
            *(float2*)(b + pl * 514 + 2 * r) = rg[kk];
        }
    };

    float accr[NPAIR_], acci[NPAIR_];
#pragma unroll
    for (int p = 0; p < NPAIR_; ++p) { accr[p] = 0.f; acci[p] = 0.f; }

    auto consume = [&](int buf) {
        if (tid < F_) {
#pragma unroll
            for (int tt = 0; tt < 2; ++tt) {   // t ascending (same order)
                float re[C_], im[C_];
#pragma unroll
                for (int c = 0; c < C_; ++c) {
                    re[c] = S[buf][c][tt * 257 + tid];
                    im[c] = S[buf][8 + c][tt * 257 + tid];
                }
                int p = 0;
#pragma unroll
                for (int c = 0; c < C_; ++c) {
#pragma unroll
                    for (int d = 0; d <= c; ++d, ++p) {
                        accr[p] += re[c]*re[d] + im[c]*im[d];
                        acci[p] += im[c]*re[d] - re[c]*im[d];
                    }
                }
            }
        }
    };

    stage(tBase); SBAR();
    writeL(0);
    __syncthreads();

    for (int k = 0; k < NS; ++k) {
        const bool more = (k + 1 < NS);
        if (more) { stage(tBase + 2 * (k + 1)); SBAR(); }  // issue-early
        consume(k & 1);
        SBAR();                      // keep writeL's vmcnt stall AFTER FMAs
        if (more) writeL((k + 1) & 1);
        __syncthreads();
    }

    if (tid < F_) {
        float* out = part + (size_t)((m * TSPLIT + chunk) * 72) * NF_ + n * F_ + tid;
#pragma unroll
        for (int p = 0; p < NPAIR_; ++p) {
            out[(size_t)(2*p)   * NF_] = accr[p];
            out[(size_t)(2*p+1) * NF_] = acci[p];
        }
    }
}

// ---------------------------------------------------------------------------
// Phase B1: reduce the chunks into the chunk-0 slot, float4-vectorized.
// ---------------------------------------------------------------------------
__global__ __launch_bounds__(256) void reduce_cov(float* __restrict__ part, int tsplit) {
    int flat = blockIdx.x * 256 + threadIdx.x;
    constexpr int NQ4 = NF_ / 4;   // 514
    if (flat >= 2 * 72 * NQ4) return;
    int idx4 = flat % NQ4;
    int z = flat / NQ4;          // z = m*72 + q
    int m = z / 72;
    int q = z % 72;
    const float4* p4 = (const float4*)(part) + ((size_t)((m * tsplit) * 72 + q) * NF_) / 4 + idx4;
    float4 s = {0.f, 0.f, 0.f, 0.f};
    for (int ch = 0; ch < tsplit; ++ch) {
        float4 v = p4[(size_t)(ch * 72) * NF_ / 4];
        s.x += v.x; s.y += v.y; s.z += v.z; s.w += v.w;
    }
    *(float4*)((float*)part + (size_t)((m * tsplit) * 72 + q) * NF_ + idx4 * 4) = s;
}

// ---------------------------------------------------------------------------
// Phase B2: wave-parallel solve. One 64-lane wave per (n,f); lane (i,j) owns
// M[i][j]. GJ inverse via shuffles (identical per-step arithmetic to the
// sequential version). 2056 waves (~8/CU) vs the old 33 waves chip-wide.
// ---------------------------------------------------------------------------
__global__ __launch_bounds__(256) void solve_w(
        const float* __restrict__ part, float* __restrict__ W, size_t yBase) {
    int widx = (blockIdx.x * 256 + threadIdx.x) >> 6;   // (n,f) index
    if (widx >= NF_) return;
    const int lane = threadIdx.x & 63;
    const int i = lane >> 3, j = lane & 7;

    const float* pv = part + widx;            // m=0, chunk 0 (reduced)
    const float* py = part + yBase + widx;    // m=1, chunk 0 (reduced)

    // M[i][j] = phi_v[i][j]/T (+ LOAD*(1+i) on diag); lower tri stored.
    {
        int a = (i > j) ? i : j, b = (i > j) ? j : i;
        int p = a*(a+1)/2 + b;
        float vr = pv[(size_t)(2*p)   * NF_] * INV_T_;
        float vi = pv[(size_t)(2*p+1) * NF_] * INV_T_;
        if (j > i) vi = -vi;                  // conj for upper triangle
        cx M0 { vr, vi };
        if (i == j) { M0.r += LOADC_; M0.i += LOADC_; }
        cx M = M0;

        // In-place Gauss-Jordan, no pivoting (diag-dominant). Same math.
#pragma unroll
        for (int k = 0; k < 8; ++k) {
            cx mkk { __shfl(M.r, (k<<3)|k, 64), __shfl(M.i, (k<<3)|k, 64) };
            cx mkj { __shfl(M.r, (k<<3)|j, 64), __shfl(M.i, (k<<3)|j, 64) };
            cx mik { __shfl(M.r, (i<<3)|k, 64), __shfl(M.i, (i<<3)|k, 64) };
            cx pk = cinv(mkk);
            cx rk = cmul(mkj, pk);            // normalized row-k element
            if (i == k) {
                M = (j == k) ? pk : rk;
            } else if (j == k) {
                cx t = cmul(mik, pk);
                M = { -t.r, -t.i };
            } else {
                M = csub(M, cmul(mik, rk));
            }
        }

        // trace(G) = sum_{i,j} M[i][j] * phi_y[j][i]/T
        int ay = (i > j) ? i : j, by = (i > j) ? j : i;
        int pt = ay*(ay+1)/2 + by;
        float yr = py[(size_t)(2*pt)   * NF_] * INV_T_;
        float yi = py[(size_t)(2*pt+1) * NF_] * INV_T_;
        if (i > j) yi = -yi;                  // phi_y[j][i], conj when j<i
        cx Yji { yr, yi };
        cx trt = cmul(M, Yji);
        float tr_r = trt.r, tr_i = trt.i;
#pragma unroll
        for (int off = 1; off < 64; off <<= 1) {
            tr_r += __shfl_xor(tr_r, off, 64);
            tr_i += __shfl_xor(tr_i, off, 64);
        }

        // g0[i] = sum_j M[i][j] * phi_y[j][0]/T  (row-reduce over j lanes)
        int p0 = j*(j+1)/2;                   // pair (j,0)
        cx y0 { py[(size_t)(2*p0)   * NF_] * INV_T_,
                py[(size_t)(2*p0+1) * NF_] * INV_T_ };
        cx g = cmul(M, y0);
#pragma unroll
        for (int off = 1; off < 8; off <<= 1) {
            g.r += __shfl_xor(g.r, off, 64);
            g.i += __shfl_xor(g.i, off, 64);
        }

        cx l { tr_r - 8.0f, tr_i - 8.0f };
        float iden = 1.0f / (l.r*l.r + l.i*l.i);
        if (j == 0) {
            cx ge = g;
            if (i == 0) ge.r -= 1.0f;
            float* w = W + (size_t)widx * 16;
            w[2*i]     = (ge.r*l.r + ge.i*l.i) * iden;   // W = conj(H)
            w[2*i + 1] = (ge.r*l.i - ge.i*l.r) * iden;
        }
    }
}

// ---------------------------------------------------------------------------
// Phase C: beamform, float4-wide. Thread owns j = 4u..4u+3 (contiguous).
// ---------------------------------------------------------------------------
__global__ __launch_bounds__(256) void beamform(
        const float* __restrict__ mix, const float* __restrict__ W,
        float* __restrict__ out) {
    constexpr int U = TF_ / 4;   // 38550
    int n = blockIdx.y;
    int u = blockIdx.x * 256 + threadIdx.x;
    if (u >= U) return;
    int j0 = 4 * u;
    int f0 = j0 % F_;

    float4 wv[4][4];
#pragma unroll
    for (int i = 0; i < 4; ++i) {
        int fi = f0 + i; if (fi >= F_) fi -= F_;
        const float4* wr = (const float4*)(W + (size_t)(n * F_ + fi) * 16);
        wv[i][0] = wr[0]; wv[i][1] = wr[1]; wv[i][2] = wr[2]; wv[i][3] = wr[3];
    }

    const float* base = mix + (size_t)n * NSTR_ + j0;
    float xr[4] = {0.f,0.f,0.f,0.f}, xi[4] = {0.f,0.f,0.f,0.f};
#pragma unroll
    for (int c = 0; c < C_; ++c) {
        float4 yr4 = *(const float4*)(base + (size_t)c * TF_);
        float4 yi4 = *(const float4*)(base + (size_t)c * TF_ + CTF_);
        float yrA[4] = {yr4.x, yr4.y, yr4.z, yr4.w};
        float yiA[4] = {yi4.x, yi4.y, yi4.z, yi4.w};
#pragma unroll
        for (int i = 0; i < 4; ++i) {
            float wr_ = (c & 1) ? wv[i][c >> 1].z : wv[i][c >> 1].x;
            float wi_ = (c & 1) ? wv[i][c >> 1].w : wv[i][c >> 1].y;
            xr[i] += wr_*yrA[i] - wi_*yiA[i];
            xi[i] += wr_*yiA[i] + wi_*yrA[i];
        }
    }
    float* op = out + (size_t)n * (2 * TF_);
    *(float4*)(op + j0)       = make_float4(xr[0], xr[1], xr[2], xr[3]);
    *(float4*)(op + TF_ + j0) = make_float4(xi[0], xi[1], xi[2], xi[3]);
}

extern "C" void kernel_launch(void* const* d_in, const int* in_sizes, int n_in,
                              void* d_out, int out_size, void* d_ws, size_t ws_size,
                              hipStream_t stream) {
    const float* mix = (const float*)d_in[0];
    // d_in[1] = target, unused by the reference
    const float* noi = (const float*)d_in[2];

    const size_t need30 = ((size_t)2 * 30 * 72 * NF_ + (size_t)16 * NF_) * 4; // ~35.6 MB
    float* part = (float*)d_ws;
    int tsplit;
    if (ws_size >= need30) {
        tsplit = 30;   // TCHUNK=20, 480 blocks (known to fit: R5 ran this)
        cov_partial<30><<<dim3(30, N_, 2), 320, 0, stream>>>(mix, noi, part);
    } else {
        tsplit = 25;   // TCHUNK=24 fallback (ws >= 29.7 MB known-good)
        cov_partial<25><<<dim3(25, N_, 2), 320, 0, stream>>>(mix, noi, part);
    }
    float* W = part + (size_t)2 * tsplit * 72 * NF_;

    reduce_cov<<<dim3((2 * 72 * (NF_ / 4) + 255) / 256), 256, 0, stream>>>(part, tsplit);
    solve_w<<<dim3((NF_ * 64 + 255) / 256), 256, 0, stream>>>(part, W, (size_t)tsplit * 72 * NF_);
    beamform<<<dim3((TF_ / 4 + 255) / 256, N_), 256, 0, stream>>>(mix, W, (float*)d_out);
}